// Round 4
// baseline (472.569 us; speedup 1.0000x reference)
//
#include <hip/hip_runtime.h>
#include <hip/hip_bf16.h>

typedef unsigned short u16;
typedef unsigned int u32;
typedef __attribute__((ext_vector_type(8))) short short8;
typedef __attribute__((ext_vector_type(4))) float f32x4;

// aliasing-safe scalar/wide types for read-only global loads
typedef u16 __attribute__((may_alias)) u16a;
typedef u32 __attribute__((may_alias)) u32a;
typedef float __attribute__((may_alias)) f32a;
typedef __attribute__((ext_vector_type(4))) u32 u32x4_t;
typedef u32x4_t __attribute__((may_alias)) u32x4;
typedef __attribute__((ext_vector_type(4))) float f32x4_t;
typedef f32x4_t __attribute__((may_alias)) f32x4a;

#define NSLOPE 0.2f
#define BNEPS  1e-5f

union U8 { short8 s; u16 u[8]; u32 w[4]; };

__device__ __forceinline__ float bf2f(u16 v) {
    union { u32 i; float f; } x; x.i = ((u32)v) << 16; return x.f;
}
__device__ __forceinline__ u16 f2bf(float f) {
    union { float f; u32 i; } x; x.f = f;
    u32 u = x.i + 0x7FFFu + ((x.i >> 16) & 1u);
    return (u16)(u >> 16);
}
__device__ __forceinline__ float lrelu(float x) { return x >= 0.f ? x : x * NSLOPE; }

// generic scalar load: element i of array p, as float
template<int BF16>
__device__ __forceinline__ float ldf(const void* p, size_t i) {
    if constexpr (BF16) return bf2f(((const u16a*)p)[i]);
    else                return ((const f32a*)p)[i];
}

// B-fragment for mfma_f32_16x16x32_bf16: lane holds B[k = ks*32 + q*8 + j][n = nt*16 + t]
template<int BF16>
__device__ __forceinline__ short8 load_bfrag(const void* W, int K, int Cn, int ks, int nt,
                                             int q, int t) {
    U8 x;
#pragma unroll
    for (int j = 0; j < 8; ++j) {
        int k = ks * 32 + q * 8 + j;
        x.u[j] = (k < K) ? f2bf(ldf<BF16>(W, (size_t)k * Cn + nt * 16 + t)) : (u16)0;
    }
    return x.s;
}

// A-fragment from LDS row-major [16][68] bf16 — scalar u16 reads (correctness-first)
__device__ __forceinline__ short8 lds_afrag(const u16* buf, int row, int ks, int q) {
    const u16* cp = buf + row * 68 + ks * 32 + q * 8;
    U8 x;
#pragma unroll
    for (int j = 0; j < 8; ++j) x.u[j] = cp[j];
    return x.s;
}

#define MFMA(a, b, c) __builtin_amdgcn_mfma_f32_16x16x32_bf16((a), (b), (c), 0, 0, 0)

// ---- dtype detector: packed-bf16 vs fp32 vote over first 64 words of `feature` ----
__global__ void dtype_detect(const u32a* __restrict__ w, int* __restrict__ flag) {
    int lane = threadIdx.x & 63;
    u32 v = w[lane];
    int e = (int)((v >> 7) & 0xFFu);           // exponent field of LOW u16 viewed as bf16
    int inr = (e >= 112 && e <= 133) ? 1 : 0;  // N(0,1) bf16 exponent range
    unsigned long long m = __ballot(inr);
    if (lane == 0) flag[0] = (__popcll(m) >= 32) ? 1 : 0;
}

// NOTE: all waves run identical trip counts (2 g-iters x 16 p-iters) -> in-loop
// __syncthreads() barriers are convergent.
template<int BF16>
__global__ __launch_bounds__(256, 2) void lfa_kernel(
    const void* __restrict__ feat,        // (131072, 32)
    const void* __restrict__ rawf,        // (131072*16, 10)
    const int*  __restrict__ nbidx,       // (131072, 16) int32
    const void* __restrict__ w_raw,
    const void* __restrict__ b_raw, const void* __restrict__ g_raw,
    const void* __restrict__ be_raw, const void* __restrict__ m_raw,
    const void* __restrict__ v_raw,
    const void* __restrict__ w_nb,
    const void* __restrict__ b_nb, const void* __restrict__ g_nb,
    const void* __restrict__ be_nb, const void* __restrict__ m_nb,
    const void* __restrict__ v_nb,
    const void* __restrict__ w_attn,
    const void* __restrict__ w_out,
    const void* __restrict__ b_out, const void* __restrict__ g_out,
    const void* __restrict__ be_out, const void* __restrict__ m_out,
    const void* __restrict__ v_out,
    const void* __restrict__ w_sc,
    const void* __restrict__ b_sc, const void* __restrict__ g_sc,
    const void* __restrict__ be_sc, const void* __restrict__ m_sc,
    const void* __restrict__ v_sc,
    void* __restrict__ outp,              // (131072, 64)
    const int* __restrict__ flag)
{
    // dtype guard: only the matching instantiation proceeds
    if (*(const volatile int*)flag != BF16) return;

    __shared__ __align__(16) u16 s_cat[4][16 * 68];
    __shared__ __align__(16) u16 s_h[4][16 * 68];
    __shared__ __align__(16) u16 s_pool[4][16 * 68];
    __shared__ float2 s_pr_raw[32];
    __shared__ float2 s_pr_nb[64];
    __shared__ float2 s_pr_out[64];
    __shared__ float2 s_pr_sc[64];

    const int tid  = threadIdx.x;
    const int lane = tid & 63;
    const int wv   = tid >> 6;
    const int t    = lane & 15;
    const int q    = lane >> 4;

    // ---- fold BN (+linear bias) into per-channel scale/bias ----
    if (tid < 64) {
        int c = tid;
        float s = ldf<BF16>(g_nb, c) * rsqrtf(ldf<BF16>(v_nb, c) + BNEPS);
        s_pr_nb[c] = make_float2(s, (ldf<BF16>(b_nb, c) - ldf<BF16>(m_nb, c)) * s + ldf<BF16>(be_nb, c));
    } else if (tid < 128) {
        int c = tid - 64;
        float s = ldf<BF16>(g_out, c) * rsqrtf(ldf<BF16>(v_out, c) + BNEPS);
        s_pr_out[c] = make_float2(s, (ldf<BF16>(b_out, c) - ldf<BF16>(m_out, c)) * s + ldf<BF16>(be_out, c));
    } else if (tid < 192) {
        int c = tid - 128;
        float s = ldf<BF16>(g_sc, c) * rsqrtf(ldf<BF16>(v_sc, c) + BNEPS);
        s_pr_sc[c] = make_float2(s, (ldf<BF16>(b_sc, c) - ldf<BF16>(m_sc, c)) * s + ldf<BF16>(be_sc, c));
    } else if (tid < 224) {
        int c = tid - 192;
        float s = ldf<BF16>(g_raw, c) * rsqrtf(ldf<BF16>(v_raw, c) + BNEPS);
        s_pr_raw[c] = make_float2(s, (ldf<BF16>(b_raw, c) - ldf<BF16>(m_raw, c)) * s + ldf<BF16>(be_raw, c));
    }
    __syncthreads();

    // ---- weight B-fragments in registers ----
    short8 wraw[2], wnb[2][4], watt[2][4], wout[2][4], wsc[4];
#pragma unroll
    for (int nt = 0; nt < 2; ++nt) wraw[nt] = load_bfrag<BF16>(w_raw, 10, 32, 0, nt, q, t);
#pragma unroll
    for (int ks = 0; ks < 2; ++ks)
#pragma unroll
        for (int nt = 0; nt < 4; ++nt) {
            wnb[ks][nt]  = load_bfrag<BF16>(w_nb,   64, 64, ks, nt, q, t);
            watt[ks][nt] = load_bfrag<BF16>(w_attn, 64, 64, ks, nt, q, t);
            wout[ks][nt] = load_bfrag<BF16>(w_out,  64, 64, ks, nt, q, t);
        }
#pragma unroll
    for (int nt = 0; nt < 4; ++nt) wsc[nt] = load_bfrag<BF16>(w_sc, 32, 64, 0, nt, q, t);

    u16* catw  = &s_cat[wv][0];
    u16* hw    = &s_h[wv][0];
    u16* poolw = &s_pool[wv][0];

    const f32x4 zf = {0.f, 0.f, 0.f, 0.f};
    const int wid = blockIdx.x * 4 + wv;
    const int nwaves = gridDim.x * 4;

    for (int g = wid; g < 8192; g += nwaves) {
        const int P0 = g * 16;

        for (int p = 0; p < 16; ++p) {
            const int P = P0 + p;
            const int bb = P >> 16;

            // ---- phase A: gather neighbors -> cat[m][0..31]; raw MLP -> cat[m][32..63] ----
            {
                int m = lane >> 2, piece = lane & 3;
                int iv = nbidx[P * 16 + m];
                size_t base = ((size_t)(bb << 16) + (size_t)iv) * 32 + piece * 8;
                if constexpr (BF16) {
                    const u32x4 v = *(const u32x4*)((const u16*)feat + base);
                    U8 gv; gv.w[0] = v.x; gv.w[1] = v.y; gv.w[2] = v.z; gv.w[3] = v.w;
#pragma unroll
                    for (int e = 0; e < 8; ++e) catw[m * 68 + piece * 8 + e] = gv.u[e];
                } else {
                    const f32x4a v0 = *(const f32x4a*)((const float*)feat + base);
                    const f32x4a v1 = *(const f32x4a*)((const float*)feat + base + 4);
#pragma unroll
                    for (int e = 0; e < 4; ++e) catw[m * 68 + piece * 8 + e]     = f2bf(v0[e]);
#pragma unroll
                    for (int e = 0; e < 4; ++e) catw[m * 68 + piece * 8 + 4 + e] = f2bf(v1[e]);
                }
            }
            {
                U8 au; au.w[0] = 0; au.w[1] = 0; au.w[2] = 0; au.w[3] = 0;
                size_t rbase = (size_t)P * 160 + (size_t)t * 10;
                if constexpr (BF16) {
                    const u32a* rp = (const u32a*)((const u16*)rawf + rbase);
                    if (q == 0) { au.w[0] = rp[0]; au.w[1] = rp[1]; au.w[2] = rp[2]; au.w[3] = rp[3]; }
                    else if (q == 1) { au.w[0] = rp[4]; }
                } else {
                    const f32a* rp = (const f32a*)rawf + rbase;
                    if (q == 0) {
#pragma unroll
                        for (int j = 0; j < 8; ++j) au.u[j] = f2bf(rp[j]);
                    } else if (q == 1) {
                        au.u[0] = f2bf(rp[8]); au.u[1] = f2bf(rp[9]);
                    }
                }
                short8 ar = au.s;
                f32x4 racc[2];
                racc[0] = MFMA(ar, wraw[0], zf);
                racc[1] = MFMA(ar, wraw[1], zf);
#pragma unroll
                for (int nt = 0; nt < 2; ++nt) {
                    int c = nt * 16 + t;
                    float2 pr = s_pr_raw[c];
#pragma unroll
                    for (int r = 0; r < 4; ++r) {
                        float x = lrelu(fmaf(racc[nt][r], pr.x, pr.y));
                        catw[(q * 4 + r) * 68 + 32 + c] = f2bf(x);
                    }
                }
            }
            __syncthreads();   // cat fully written before fragment reads

            // ---- phase B: h = lrelu(bn(cat @ w_nb)) ----
            {
                short8 a0 = lds_afrag(catw, t, 0, q);
                short8 a1 = lds_afrag(catw, t, 1, q);
                float hv[4][4];
#pragma unroll
                for (int nt = 0; nt < 4; ++nt) {
                    f32x4 a = zf;
                    a = MFMA(a0, wnb[0][nt], a);
                    a = MFMA(a1, wnb[1][nt], a);
                    float2 pr = s_pr_nb[nt * 16 + t];
#pragma unroll
                    for (int r = 0; r < 4; ++r) {
                        hv[nt][r] = lrelu(fmaf(a[r], pr.x, pr.y));
                        hw[(q * 4 + r) * 68 + nt * 16 + t] = f2bf(hv[nt][r]);
                    }
                }
                __syncthreads();   // h fully written before fragment reads

                // ---- phase C: scores = h @ w_attn; softmax over m; pool ----
                short8 h0 = lds_afrag(hw, t, 0, q);
                short8 h1 = lds_afrag(hw, t, 1, q);
                float pooled[4];
#pragma unroll
                for (int nt = 0; nt < 4; ++nt) {
                    f32x4 s = zf;
                    s = MFMA(h0, watt[0][nt], s);
                    s = MFMA(h1, watt[1][nt], s);
                    float mx = fmaxf(fmaxf(s[0], s[1]), fmaxf(s[2], s[3]));
                    mx = fmaxf(mx, __shfl_xor(mx, 16));
                    mx = fmaxf(mx, __shfl_xor(mx, 32));
                    float num = 0.f, den = 0.f;
#pragma unroll
                    for (int r = 0; r < 4; ++r) {
                        float e = __expf(s[r] - mx);
                        num += e * hv[nt][r];
                        den += e;
                    }
                    num += __shfl_xor(num, 16); den += __shfl_xor(den, 16);
                    num += __shfl_xor(num, 32); den += __shfl_xor(den, 32);
                    pooled[nt] = num / den;
                }
                float pv = (q == 0) ? pooled[0] : (q == 1) ? pooled[1]
                         : (q == 2) ? pooled[2] : pooled[3];
                poolw[p * 68 + q * 16 + t] = f2bf(pv);
            }
            __syncthreads();   // pool row p written; also orders next-p cat overwrite
        }

        // ---- epilogue: out = bn(pooled @ w_out); sc = bn(feat @ w_sc); lrelu(sum) ----
        short8 pf0 = lds_afrag(poolw, t, 0, q);
        short8 pf1 = lds_afrag(poolw, t, 1, q);
        U8 sxu;
        {
            size_t base = ((size_t)(P0 + t)) * 32 + q * 8;
            if constexpr (BF16) {
                const u32x4 fv = *(const u32x4*)((const u16*)feat + base);
                sxu.w[0] = fv.x; sxu.w[1] = fv.y; sxu.w[2] = fv.z; sxu.w[3] = fv.w;
            } else {
                const f32x4a v0 = *(const f32x4a*)((const float*)feat + base);
                const f32x4a v1 = *(const f32x4a*)((const float*)feat + base + 4);
#pragma unroll
                for (int e = 0; e < 4; ++e) sxu.u[e]     = f2bf(v0[e]);
#pragma unroll
                for (int e = 0; e < 4; ++e) sxu.u[4 + e] = f2bf(v1[e]);
            }
        }
        short8 scf = sxu.s;
#pragma unroll
        for (int nt = 0; nt < 4; ++nt) {
            f32x4 oa = zf;
            oa = MFMA(pf0, wout[0][nt], oa);
            oa = MFMA(pf1, wout[1][nt], oa);
            f32x4 sa = MFMA(scf, wsc[nt], zf);
            float2 po = s_pr_out[nt * 16 + t];
            float2 ps = s_pr_sc[nt * 16 + t];
#pragma unroll
            for (int r = 0; r < 4; ++r) {
                float o  = fmaf(oa[r], po.x, po.y);
                float s2 = fmaf(sa[r], ps.x, ps.y);
                float y  = lrelu(o + s2);
                size_t oi = (size_t)(P0 + q * 4 + r) * 64 + nt * 16 + t;
                if constexpr (BF16) ((u16*)outp)[oi] = f2bf(y);
                else                ((float*)outp)[oi] = y;
            }
        }
        __syncthreads();   // poolw consumed before next g overwrites it
    }
}

extern "C" void kernel_launch(void* const* d_in, const int* in_sizes, int n_in,
                              void* d_out, int out_size, void* d_ws, size_t ws_size,
                              hipStream_t stream) {
    const void* feat   = d_in[0];
    const void* rawf   = d_in[1];
    const int*  nbidx  = (const int*)d_in[2];
    const void* w_raw  = d_in[3];
    const void* b_raw  = d_in[4];
    const void* g_raw  = d_in[5];
    const void* be_raw = d_in[6];
    const void* m_raw  = d_in[7];
    const void* v_raw  = d_in[8];
    const void* w_nb   = d_in[9];
    const void* b_nb   = d_in[10];
    const void* g_nb   = d_in[11];
    const void* be_nb  = d_in[12];
    const void* m_nb   = d_in[13];
    const void* v_nb   = d_in[14];
    const void* w_attn = d_in[15];
    const void* w_out  = d_in[16];
    const void* b_out  = d_in[17];
    const void* g_out  = d_in[18];
    const void* be_out = d_in[19];
    const void* m_out  = d_in[20];
    const void* v_out  = d_in[21];
    const void* w_sc   = d_in[22];
    const void* b_sc   = d_in[23];
    const void* g_sc   = d_in[24];
    const void* be_sc  = d_in[25];
    const void* m_sc   = d_in[26];
    const void* v_sc   = d_in[27];

    int* flag = (int*)d_ws;

    hipLaunchKernelGGL(dtype_detect, dim3(1), dim3(64), 0, stream,
                       (const u32a*)feat, flag);

    hipLaunchKernelGGL((lfa_kernel<0>), dim3(1024), dim3(256), 0, stream,
                       feat, rawf, nbidx,
                       w_raw, b_raw, g_raw, be_raw, m_raw, v_raw,
                       w_nb, b_nb, g_nb, be_nb, m_nb, v_nb,
                       w_attn,
                       w_out, b_out, g_out, be_out, m_out, v_out,
                       w_sc, b_sc, g_sc, be_sc, m_sc, v_sc,
                       d_out, flag);

    hipLaunchKernelGGL((lfa_kernel<1>), dim3(1024), dim3(256), 0, stream,
                       feat, rawf, nbidx,
                       w_raw, b_raw, g_raw, be_raw, m_raw, v_raw,
                       w_nb, b_nb, g_nb, be_nb, m_nb, v_nb,
                       w_attn,
                       w_out, b_out, g_out, be_out, m_out, v_out,
                       w_sc, b_sc, g_sc, be_sc, m_sc, v_sc,
                       d_out, flag);
}

// Round 5
// 338.236 us; speedup vs baseline: 1.3972x; 1.3972x over previous
//
#include <hip/hip_runtime.h>
#include <hip/hip_bf16.h>

typedef unsigned short u16;
typedef unsigned int u32;
typedef __attribute__((ext_vector_type(8))) short short8;
typedef __attribute__((ext_vector_type(4))) float f32x4;

// aliasing-safe types for type-punned global loads
typedef float __attribute__((may_alias)) f32a;
typedef __attribute__((ext_vector_type(2))) float f32x2_t;
typedef f32x2_t __attribute__((may_alias)) f32x2a;
typedef __attribute__((ext_vector_type(4))) float f32x4_t;
typedef f32x4_t __attribute__((may_alias)) f32x4a;

#define NSLOPE 0.2f
#define BNEPS  1e-5f

union U8 { short8 s; u16 u[8]; u32 w[4]; };

__device__ __forceinline__ u16 f2bf(float f) {
    union { float f; u32 i; } x; x.f = f;
    u32 u = x.i + 0x7FFFu + ((x.i >> 16) & 1u);
    return (u16)(u >> 16);
}
__device__ __forceinline__ float lrelu(float x) { return x >= 0.f ? x : x * NSLOPE; }

// B-fragment for mfma_f32_16x16x32_bf16 from fp32 global W:
// lane holds B[k = ks*32 + q*8 + j][n = nt*16 + t]
__device__ __forceinline__ short8 load_bfrag(const void* W, int K, int Cn, int ks, int nt,
                                             int q, int t) {
    U8 x;
#pragma unroll
    for (int j = 0; j < 8; ++j) {
        int k = ks * 32 + q * 8 + j;
        x.u[j] = (k < K) ? f2bf(((const f32a*)W)[(size_t)k * Cn + nt * 16 + t]) : (u16)0;
    }
    return x.s;
}

// A-fragment from per-wave LDS tile row-major [16][68] bf16 (scalar u16 reads;
// backend merges; same-array dependence keeps write->read order, same-wave DS is in-order)
__device__ __forceinline__ short8 lds_afrag(const u16* buf, int row, int ks, int q) {
    const u16* cp = buf + row * 68 + ks * 32 + q * 8;
    U8 x;
#pragma unroll
    for (int j = 0; j < 8; ++j) x.u[j] = cp[j];
    return x.s;
}

__device__ __forceinline__ float ldf(const void* p, size_t i) { return ((const f32a*)p)[i]; }

#define MFMA(a, b, c) __builtin_amdgcn_mfma_f32_16x16x32_bf16((a), (b), (c), 0, 0, 0)

struct G8 { float v[8]; };

// One wave = one group of 16 points. LDS tiles are PER-WAVE: no in-loop barriers.
__global__ __launch_bounds__(256, 3) void lfa_kernel(
    const void* __restrict__ feat,        // (131072, 32) fp32
    const void* __restrict__ rawf,        // (131072*16, 10) fp32
    const int*  __restrict__ nbidx,       // (131072, 16) int32
    const void* __restrict__ w_raw,
    const void* __restrict__ b_raw, const void* __restrict__ g_raw,
    const void* __restrict__ be_raw, const void* __restrict__ m_raw,
    const void* __restrict__ v_raw,
    const void* __restrict__ w_nb,
    const void* __restrict__ b_nb, const void* __restrict__ g_nb,
    const void* __restrict__ be_nb, const void* __restrict__ m_nb,
    const void* __restrict__ v_nb,
    const void* __restrict__ w_attn,
    const void* __restrict__ w_out,
    const void* __restrict__ b_out, const void* __restrict__ g_out,
    const void* __restrict__ be_out, const void* __restrict__ m_out,
    const void* __restrict__ v_out,
    const void* __restrict__ w_sc,
    const void* __restrict__ b_sc, const void* __restrict__ g_sc,
    const void* __restrict__ be_sc, const void* __restrict__ m_sc,
    const void* __restrict__ v_sc,
    float* __restrict__ outp)             // (131072, 64) fp32
{
    __shared__ __align__(16) u16 s_cat[4][16 * 68];
    __shared__ __align__(16) u16 s_h[4][16 * 68];
    __shared__ __align__(16) u16 s_pool[4][16 * 68];
    __shared__ float2 s_pr_raw[32];
    __shared__ float2 s_pr_nb[64];
    __shared__ float2 s_pr_out[64];
    __shared__ float2 s_pr_sc[64];

    const int tid  = threadIdx.x;
    const int lane = tid & 63;
    const int wv   = tid >> 6;
    const int t    = lane & 15;
    const int q    = lane >> 4;

    // ---- fold BN (+linear bias) into per-channel scale/bias ----
    if (tid < 64) {
        int c = tid;
        float s = ldf(g_nb, c) * rsqrtf(ldf(v_nb, c) + BNEPS);
        s_pr_nb[c] = make_float2(s, (ldf(b_nb, c) - ldf(m_nb, c)) * s + ldf(be_nb, c));
    } else if (tid < 128) {
        int c = tid - 64;
        float s = ldf(g_out, c) * rsqrtf(ldf(v_out, c) + BNEPS);
        s_pr_out[c] = make_float2(s, (ldf(b_out, c) - ldf(m_out, c)) * s + ldf(be_out, c));
    } else if (tid < 192) {
        int c = tid - 128;
        float s = ldf(g_sc, c) * rsqrtf(ldf(v_sc, c) + BNEPS);
        s_pr_sc[c] = make_float2(s, (ldf(b_sc, c) - ldf(m_sc, c)) * s + ldf(be_sc, c));
    } else if (tid < 224) {
        int c = tid - 192;
        float s = ldf(g_raw, c) * rsqrtf(ldf(v_raw, c) + BNEPS);
        s_pr_raw[c] = make_float2(s, (ldf(b_raw, c) - ldf(m_raw, c)) * s + ldf(be_raw, c));
    }
    __syncthreads();   // the ONLY block-wide barrier (BN tables shared by all waves)

    // ---- loop-phase weight B-fragments in registers (w_out/w_sc reloaded in epilogue) ----
    short8 wraw[2], wnb[2][4], watt[2][4];
#pragma unroll
    for (int nt = 0; nt < 2; ++nt) wraw[nt] = load_bfrag(w_raw, 10, 32, 0, nt, q, t);
#pragma unroll
    for (int ks = 0; ks < 2; ++ks)
#pragma unroll
        for (int nt = 0; nt < 4; ++nt) {
            wnb[ks][nt]  = load_bfrag(w_nb,   64, 64, ks, nt, q, t);
            watt[ks][nt] = load_bfrag(w_attn, 64, 64, ks, nt, q, t);
        }

    u16* catw  = &s_cat[wv][0];
    u16* hw    = &s_h[wv][0];
    u16* poolw = &s_pool[wv][0];

    const f32x4 zf = {0.f, 0.f, 0.f, 0.f};
    const int g  = blockIdx.x * 4 + wv;     // 8192 groups, grid 2048 x 4 waves
    const int P0 = g * 16;
    const int bb = P0 >> 16;                // group never straddles batch boundary
    const size_t fb = (size_t)bb << 16;

    const int m_ = lane >> 2;               // gather: neighbor index this lane handles
    const int pc = lane & 3;                // gather: 8-float piece

    // gather loader: feat row (fb + ix), floats [pc*8, pc*8+8)
    auto load_gather = [&](int ix) {
        const float* fp = (const float*)feat + (fb + (size_t)ix) * 32 + pc * 8;
        f32x4a a = *(const f32x4a*)fp;
        f32x4a b = *(const f32x4a*)(fp + 4);
        G8 r;
        r.v[0]=a.x; r.v[1]=a.y; r.v[2]=a.z; r.v[3]=a.w;
        r.v[4]=b.x; r.v[5]=b.y; r.v[6]=b.z; r.v[7]=b.w;
        return r;
    };
    // raw loader for point p: A-frag source, lane(t,q): k = q*8+j
    auto load_raw = [&](int p) {
        G8 r;
#pragma unroll
        for (int j = 0; j < 8; ++j) r.v[j] = 0.f;
        const f32a* rp = (const f32a*)rawf + (size_t)(P0 + p) * 160 + (size_t)t * 10;
        if (q == 0) {           // 8B-aligned f32x2 loads (t*40 % 8 == 0)
            f32x2a a = *(const f32x2a*)rp;
            f32x2a b = *(const f32x2a*)(rp + 2);
            f32x2a c = *(const f32x2a*)(rp + 4);
            f32x2a d = *(const f32x2a*)(rp + 6);
            r.v[0]=a.x; r.v[1]=a.y; r.v[2]=b.x; r.v[3]=b.y;
            r.v[4]=c.x; r.v[5]=c.y; r.v[6]=d.x; r.v[7]=d.y;
        } else if (q == 1) {
            f32x2a a = *(const f32x2a*)(rp + 8);
            r.v[0]=a.x; r.v[1]=a.y;
        }
        return r;
    };

    // ---- software-pipeline preamble ----
    int ixA = nbidx[P0 * 16 + m_];          // idx for p=0
    int ixB = nbidx[(P0 + 1) * 16 + m_];    // idx for p=1
    G8 gA = load_gather(ixA);               // gather for p=0
    G8 rA = load_raw(0);                    // raw for p=0

#pragma unroll 1
    for (int p = 0; p < 16; ++p) {
        // ---- issue next iteration's loads first (latency cover) ----
        G8 gB, rB; int ixC = ixB;
        if (p < 15) {
            gB = load_gather(ixB);
            rB = load_raw(p + 1);
            ixC = nbidx[(P0 + ((p + 2 < 16) ? p + 2 : 15)) * 16 + m_];
        } else {
            gB = gA; rB = rA;
        }

        // ---- phase A: gather -> cat[m][0..31]; raw MLP -> cat[m][32..63] ----
        {
#pragma unroll
            for (int e = 0; e < 8; ++e) catw[m_ * 68 + pc * 8 + e] = f2bf(gA.v[e]);
        }
        {
            U8 au;
#pragma unroll
            for (int j = 0; j < 8; ++j) au.u[j] = f2bf(rA.v[j]);
            short8 ar = au.s;
            f32x4 racc[2];
            racc[0] = MFMA(ar, wraw[0], zf);
            racc[1] = MFMA(ar, wraw[1], zf);
#pragma unroll
            for (int nt = 0; nt < 2; ++nt) {
                int c = nt * 16 + t;
                float2 pr = s_pr_raw[c];
#pragma unroll
                for (int r = 0; r < 4; ++r) {
                    float x = lrelu(fmaf(racc[nt][r], pr.x, pr.y));
                    catw[(q * 4 + r) * 68 + 32 + c] = f2bf(x);
                }
            }
        }

        // ---- phase B: h = lrelu(bn(cat @ w_nb)) ----
        short8 a0 = lds_afrag(catw, t, 0, q);
        short8 a1 = lds_afrag(catw, t, 1, q);
        float hv[4][4];
#pragma unroll
        for (int nt = 0; nt < 4; ++nt) {
            f32x4 a = zf;
            a = MFMA(a0, wnb[0][nt], a);
            a = MFMA(a1, wnb[1][nt], a);
            float2 pr = s_pr_nb[nt * 16 + t];
#pragma unroll
            for (int r = 0; r < 4; ++r) {
                hv[nt][r] = lrelu(fmaf(a[r], pr.x, pr.y));
                hw[(q * 4 + r) * 68 + nt * 16 + t] = f2bf(hv[nt][r]);
            }
        }

        // ---- phase C: scores = h @ w_attn; softmax over m; pool ----
        short8 h0 = lds_afrag(hw, t, 0, q);
        short8 h1 = lds_afrag(hw, t, 1, q);
        float pooled[4];
#pragma unroll
        for (int nt = 0; nt < 4; ++nt) {
            f32x4 s = zf;
            s = MFMA(h0, watt[0][nt], s);
            s = MFMA(h1, watt[1][nt], s);
            float mx = fmaxf(fmaxf(s[0], s[1]), fmaxf(s[2], s[3]));
            mx = fmaxf(mx, __shfl_xor(mx, 16));
            mx = fmaxf(mx, __shfl_xor(mx, 32));
            float num = 0.f, den = 0.f;
#pragma unroll
            for (int r = 0; r < 4; ++r) {
                float e = __expf(s[r] - mx);
                num += e * hv[nt][r];
                den += e;
            }
            num += __shfl_xor(num, 16); den += __shfl_xor(den, 16);
            num += __shfl_xor(num, 32); den += __shfl_xor(den, 32);
            pooled[nt] = num / den;
        }
        float pv = (q == 0) ? pooled[0] : (q == 1) ? pooled[1]
                 : (q == 2) ? pooled[2] : pooled[3];
        poolw[p * 68 + q * 16 + t] = f2bf(pv);

        // rotate pipeline buffers
        gA = gB; rA = rB; ixB = ixC;
    }

    // ---- epilogue: out = bn(pooled @ w_out); sc = bn(feat @ w_sc); lrelu(sum) ----
    // (w_out / w_sc fragments reloaded here so they don't occupy VGPRs in the loop)
    short8 wout[2][4], wsc[4];
#pragma unroll
    for (int ks = 0; ks < 2; ++ks)
#pragma unroll
        for (int nt = 0; nt < 4; ++nt) wout[ks][nt] = load_bfrag(w_out, 64, 64, ks, nt, q, t);
#pragma unroll
    for (int nt = 0; nt < 4; ++nt) wsc[nt] = load_bfrag(w_sc, 32, 64, 0, nt, q, t);

    short8 pf0 = lds_afrag(poolw, t, 0, q);
    short8 pf1 = lds_afrag(poolw, t, 1, q);
    U8 sxu;
    {
        const float* fp = (const float*)feat + (size_t)(P0 + t) * 32 + q * 8;
        f32x4a v0 = *(const f32x4a*)fp;
        f32x4a v1 = *(const f32x4a*)(fp + 4);
        sxu.u[0]=f2bf(v0.x); sxu.u[1]=f2bf(v0.y); sxu.u[2]=f2bf(v0.z); sxu.u[3]=f2bf(v0.w);
        sxu.u[4]=f2bf(v1.x); sxu.u[5]=f2bf(v1.y); sxu.u[6]=f2bf(v1.z); sxu.u[7]=f2bf(v1.w);
    }
    short8 scf = sxu.s;
#pragma unroll
    for (int nt = 0; nt < 4; ++nt) {
        f32x4 oa = zf;
        oa = MFMA(pf0, wout[0][nt], oa);
        oa = MFMA(pf1, wout[1][nt], oa);
        f32x4 sa = MFMA(scf, wsc[nt], zf);
        float2 po = s_pr_out[nt * 16 + t];
        float2 ps = s_pr_sc[nt * 16 + t];
#pragma unroll
        for (int r = 0; r < 4; ++r) {
            float o  = fmaf(oa[r], po.x, po.y);
            float s2 = fmaf(sa[r], ps.x, ps.y);
            outp[(size_t)(P0 + q * 4 + r) * 64 + nt * 16 + t] = lrelu(o + s2);
        }
    }
}

extern "C" void kernel_launch(void* const* d_in, const int* in_sizes, int n_in,
                              void* d_out, int out_size, void* d_ws, size_t ws_size,
                              hipStream_t stream) {
    hipLaunchKernelGGL(lfa_kernel, dim3(2048), dim3(256), 0, stream,
                       d_in[0], d_in[1], (const int*)d_in[2],
                       d_in[3], d_in[4], d_in[5], d_in[6], d_in[7], d_in[8],
                       d_in[9], d_in[10], d_in[11], d_in[12], d_in[13], d_in[14],
                       d_in[15],
                       d_in[16], d_in[17], d_in[18], d_in[19], d_in[20], d_in[21],
                       d_in[22], d_in[23], d_in[24], d_in[25], d_in[26], d_in[27],
                       (float*)d_out);
}